// Round 5
// baseline (360.055 us; speedup 1.0000x reference)
//
#include <hip/hip_runtime.h>

typedef unsigned short u16;
typedef unsigned int uint32;
typedef __bf16 bf16x8 __attribute__((ext_vector_type(8)));
typedef float f32x4 __attribute__((ext_vector_type(4)));

static constexpr int Gg = 64;
static constexpr int Nn = 2048;
static constexpr int Ee = 16384;
static constexpr int GN = Gg * Nn;   // 131072
static constexpr int GE = Gg * Ee;   // 1048576

__device__ __forceinline__ u16 f2u(float f) {  // round-to-nearest-even bf16
    uint32 i = __float_as_uint(f);
    uint32 r = (i + 0x7FFFu + ((i >> 16) & 1u)) >> 16;
    return (u16)r;
}
__device__ __forceinline__ float lo16f(uint32 v) { return __uint_as_float(v << 16); }
__device__ __forceinline__ float hi16f(uint32 v) { return __uint_as_float(v & 0xffff0000u); }

// ---------------- setup kernels ----------------

__global__ void k_zero(int* __restrict__ p) {
    p[blockIdx.x * 256 + threadIdx.x] = 0;
}

__global__ void k_count(const int* __restrict__ ei, int* __restrict__ deg) {
    int e = blockIdx.x * 256 + threadIdx.x;
    atomicAdd(&deg[ei[GE + e]], 1);   // row 1 = dst (global ids)
}

// per-graph exclusive scan -> graph-major CSR offsets; also dis/invdeg
__global__ void k_scan(const int* __restrict__ deg, int* __restrict__ pos_gm,
                       int* __restrict__ cur, float* __restrict__ dis,
                       float* __restrict__ invdeg) {
    int g = blockIdx.x, t = threadIdx.x;
    __shared__ int s[256];
    int base = g * Nn + t * 8;
    int c[8]; int tot = 0;
    #pragma unroll
    for (int j = 0; j < 8; ++j) { c[j] = deg[base + j]; tot += c[j]; }
    s[t] = tot; __syncthreads();
    for (int off = 1; off < 256; off <<= 1) {
        int v = (t >= off) ? s[t - off] : 0;
        __syncthreads();
        s[t] += v;
        __syncthreads();
    }
    int run = g * Ee + (s[t] - tot);
    #pragma unroll
    for (int j = 0; j < 8; ++j) {
        pos_gm[base + j] = run;
        cur[base + j] = run;
        float d = 1.0f + (float)c[j];
        dis[base + j] = rsqrtf(d);
        invdeg[base + j] = 1.0f / d;
        run += c[j];
    }
    if (g == 0 && t == 0) pos_gm[GN] = GE;
}

// rank-within-(g,i) atomic: 131072 cursors, ~8 collisions each
__global__ void k_scatter(const int* __restrict__ ei, const float* __restrict__ dis,
                          int* __restrict__ cur, int2* __restrict__ nme) {
    int e = blockIdx.x * 256 + threadIdx.x;
    int s = ei[e];          // src gid
    int d = ei[GE + e];     // dst gid
    int p = atomicAdd(&cur[d], 1);
    nme[p] = make_int2(s, __float_as_int(dis[s] * dis[d]));
}

// transpose bottom half of Wm -> Wt[c][f] bf16
__global__ void k_trans(const float* __restrict__ Wm, u16* __restrict__ Wt) {
    int idx = blockIdx.x * 256 + threadIdx.x;   // 16384
    int f = idx >> 7, c = idx & 127;
    Wt[c * 128 + f] = f2u(Wm[(128 + f) * 128 + c]);
}

// A[g] = (ce @ Wm_top) + bm, ce = (x[center]*invdeg + incident edges) @ W1 + b1
__global__ void k_A(const float* __restrict__ x, const int* __restrict__ center,
                    const float* __restrict__ invdeg, const int* __restrict__ pos_gm,
                    const int2* __restrict__ nme,
                    const float* __restrict__ W1, const float* __restrict__ b1,
                    const float* __restrict__ Wm, const float* __restrict__ bm,
                    float* __restrict__ A) {
    int g = blockIdx.x, t = threadIdx.x;   // 128 threads
    __shared__ float cepre[128], ce[128];
    int cg = (g << 11) + center[g];
    float v = x[cg * 128 + t] * invdeg[cg];
    int p0 = pos_gm[cg], p1 = pos_gm[cg + 1];
    for (int e = p0; e < p1; ++e) {          // usually empty (center has no in-edges)
        int2 m = nme[e];
        v += __int_as_float(m.y) * x[m.x * 128 + t];
    }
    cepre[t] = v; __syncthreads();
    float a = b1[t];
    #pragma unroll 8
    for (int f = 0; f < 128; ++f) a += cepre[f] * W1[f * 128 + t];
    ce[t] = a; __syncthreads();
    float o = bm[t];
    #pragma unroll 8
    for (int h = 0; h < 128; ++h) o += ce[h] * Wm[h * 128 + t];
    A[g * 128 + t] = o;
}

// ---------------- mask + y GEMM (MFMA), persistent blocks, packed xy ----------------
// xy row (256 u16): group k (u16[4k..4k+4)) = { y[2k], y[2k+1], x[2k], x[2k+1] } bf16
__global__ __launch_bounds__(256) void k_masky(const float* __restrict__ x,
                                               const u16* __restrict__ Wt,
                                               const float* __restrict__ A,
                                               u16* __restrict__ xy) {
    __shared__ u16 sWt[16384];
    __shared__ float sA[128];
    __shared__ float sC[4][2048];
    int t = threadIdx.x;
    #pragma unroll
    for (int j = 0; j < 8; ++j)
        ((uint4*)sWt)[j * 256 + t] = ((const uint4*)Wt)[j * 256 + t];

    int w = t >> 6, l = t & 63;
    int lm = l & 15, lq = l >> 4;

    for (int tile = blockIdx.x; tile < 2048; tile += 512) {
        int g = tile >> 5;
        __syncthreads();                       // covers sWt (1st iter) + sA reuse
        if (t < 128) sA[t] = A[g * 128 + t];
        __syncthreads();

        int row0 = tile * 64 + w * 16;
        f32x4 acc[8] = {};
        #pragma unroll
        for (int ks = 0; ks < 4; ++ks) {
            const float* xp = x + (row0 + lm) * 128 + ks * 32 + lq * 8;
            float4 x0 = *(const float4*)(xp);
            float4 x1 = *(const float4*)(xp + 4);
            union { u16 u[8]; bf16x8 v; } af;
            af.u[0] = f2u(x0.x); af.u[1] = f2u(x0.y); af.u[2] = f2u(x0.z); af.u[3] = f2u(x0.w);
            af.u[4] = f2u(x1.x); af.u[5] = f2u(x1.y); af.u[6] = f2u(x1.z); af.u[7] = f2u(x1.w);
            #pragma unroll
            for (int ct = 0; ct < 8; ++ct) {
                bf16x8 b = *reinterpret_cast<const bf16x8*>(sWt + (ct * 16 + lm) * 128 + ks * 32 + lq * 8);
                acc[ct] = __builtin_amdgcn_mfma_f32_16x16x32_bf16(af.v, b, acc[ct], 0, 0, 0);
            }
        }

        // per-wave C tile: wave-internal LDS round-trip, no block barrier needed
        float* myC = sC[w];
        #pragma unroll
        for (int ct = 0; ct < 8; ++ct)
            #pragma unroll
            for (int r = 0; r < 4; ++r)
                myC[(lq * 4 + r) * 128 + ct * 16 + lm] = acc[ct][r];

        int lr = l >> 2;
        int cc = (l & 3) * 32;
        int grow = row0 + lr;
        const float* xr = x + grow * 128 + cc;
        u16* orow = xy + grow * 256;
        #pragma unroll
        for (int j = 0; j < 4; ++j) {
            int c0 = cc + j * 8;
            float4 ca = *(const float4*)(myC + lr * 128 + c0);
            float4 cb = *(const float4*)(myC + lr * 128 + c0 + 4);
            float4 xa = *(const float4*)(xr + j * 8);
            float4 xd = *(const float4*)(xr + j * 8 + 4);
            float m0 = fmaxf(ca.x + sA[c0 + 0], 0.f) * xa.x;
            float m1 = fmaxf(ca.y + sA[c0 + 1], 0.f) * xa.y;
            float m2 = fmaxf(ca.z + sA[c0 + 2], 0.f) * xa.z;
            float m3 = fmaxf(ca.w + sA[c0 + 3], 0.f) * xa.w;
            float m4 = fmaxf(cb.x + sA[c0 + 4], 0.f) * xd.x;
            float m5 = fmaxf(cb.y + sA[c0 + 5], 0.f) * xd.y;
            float m6 = fmaxf(cb.z + sA[c0 + 6], 0.f) * xd.z;
            float m7 = fmaxf(cb.w + sA[c0 + 7], 0.f) * xd.w;
            uint4 q1, q2;
            q1.x = (uint32)f2u(m0) | ((uint32)f2u(m1) << 16);
            q1.y = (uint32)f2u(xa.x) | ((uint32)f2u(xa.y) << 16);
            q1.z = (uint32)f2u(m2) | ((uint32)f2u(m3) << 16);
            q1.w = (uint32)f2u(xa.z) | ((uint32)f2u(xa.w) << 16);
            q2.x = (uint32)f2u(m4) | ((uint32)f2u(m5) << 16);
            q2.y = (uint32)f2u(xd.x) | ((uint32)f2u(xd.y) << 16);
            q2.z = (uint32)f2u(m6) | ((uint32)f2u(m7) << 16);
            q2.w = (uint32)f2u(xd.z) | ((uint32)f2u(xd.w) << 16);
            *(uint4*)(orow + 2 * c0) = q1;
            *(uint4*)(orow + 2 * c0 + 8) = q2;
        }
    }
}

// ---------------- XCD-local propagation: partial sums over 8-graph groups ----------------
// blockIdx = p + 8*c : group p -> XCD p (heuristic), c = 16-node chunk.
// Wave handles 4 nodes; acc in VGPRs; writes zp[p][node][256] fp32 (xy-interleaved).
__global__ __launch_bounds__(256) void k_propx(const u16* __restrict__ xy,
                                               const float* __restrict__ invdeg,
                                               const int* __restrict__ pos_gm,
                                               const int2* __restrict__ nme,
                                               float* __restrict__ zp) {
    int b = blockIdx.x;
    int p = b & 7, c = b >> 3;
    int t = threadIdx.x, w = t >> 6, l = t & 63;
    int d0 = c * 16 + w * 4;
    float aY0[4] = {}, aY1[4] = {}, aX0[4] = {}, aX1[4] = {};
    for (int g = p * 8; g < p * 8 + 8; ++g) {
        int gb = (g << 11) + d0;
        #pragma unroll
        for (int d = 0; d < 4; ++d) {
            int gid = gb + d;
            float cf = invdeg[gid];
            uint2 v = *(const uint2*)(xy + gid * 256 + 4 * l);
            aY0[d] += cf * lo16f(v.x); aY1[d] += cf * hi16f(v.x);
            aX0[d] += cf * lo16f(v.y); aX1[d] += cf * hi16f(v.y);
        }
        #pragma unroll
        for (int d = 0; d < 4; ++d) {
            int gid = gb + d;
            int e = pos_gm[gid], e1 = pos_gm[gid + 1];
            for (; e + 1 < e1; e += 2) {
                int2 m0 = nme[e], m1 = nme[e + 1];
                uint2 v0 = *(const uint2*)(xy + m0.x * 256 + 4 * l);
                uint2 v1 = *(const uint2*)(xy + m1.x * 256 + 4 * l);
                float c0 = __int_as_float(m0.y), c1 = __int_as_float(m1.y);
                aY0[d] += c0 * lo16f(v0.x) + c1 * lo16f(v1.x);
                aY1[d] += c0 * hi16f(v0.x) + c1 * hi16f(v1.x);
                aX0[d] += c0 * lo16f(v0.y) + c1 * lo16f(v1.y);
                aX1[d] += c0 * hi16f(v0.y) + c1 * hi16f(v1.y);
            }
            if (e < e1) {
                int2 m0 = nme[e];
                uint2 v0 = *(const uint2*)(xy + m0.x * 256 + 4 * l);
                float c0 = __int_as_float(m0.y);
                aY0[d] += c0 * lo16f(v0.x); aY1[d] += c0 * hi16f(v0.x);
                aX0[d] += c0 * lo16f(v0.y); aX1[d] += c0 * hi16f(v0.y);
            }
        }
    }
    #pragma unroll
    for (int d = 0; d < 4; ++d) {
        float4 o = make_float4(aY0[d], aY1[d], aX0[d], aX1[d]);
        *(float4*)(zp + (((p << 11) + d0 + d) << 8) + 4 * l) = o;
    }
}

// ---------------- reduce partials + fused output matvecs ----------------
__global__ __launch_bounds__(256) void k_reduce(const float* __restrict__ zp,
                                                const float* __restrict__ W2, const float* __restrict__ b2,
                                                const float* __restrict__ W3, const float* __restrict__ b3,
                                                float* __restrict__ out) {
    int i = blockIdx.x;   // node 0..2046
    int t = threadIdx.x;
    __shared__ float zm[128], zxm[128];
    float s = 0.f;
    #pragma unroll
    for (int p = 0; p < 8; ++p) s += zp[(((p << 11) + i) << 8) + t];
    s *= (1.0f / 64.0f);
    int k = t >> 2, r = t & 3;
    if (r < 2) zm[2 * k + r] = s; else zxm[2 * k + (r - 2)] = s;
    __syncthreads();
    int cc = t & 127;
    if (t < 128) {
        float acc = b2[cc];
        #pragma unroll 8
        for (int f = 0; f < 128; ++f) acc += zm[f] * W2[f * 128 + cc];
        out[i * 128 + cc] = acc;
    } else {
        float acc = b3[cc];
        #pragma unroll 8
        for (int f = 0; f < 128; ++f) acc += (zxm[f] - zm[f]) * W3[f * 128 + cc];
        out[2047 * 128 + i * 128 + cc] = acc;
    }
}

// ---------------- launch ----------------

extern "C" void kernel_launch(void* const* d_in, const int* in_sizes, int n_in,
                              void* d_out, int out_size, void* d_ws, size_t ws_size,
                              hipStream_t stream) {
    const float* x    = (const float*)d_in[0];
    const int* ei     = (const int*)d_in[1];
    const int* center = (const int*)d_in[3];
    const float* W1 = (const float*)d_in[4];
    const float* b1 = (const float*)d_in[5];
    const float* W2 = (const float*)d_in[6];
    const float* b2 = (const float*)d_in[7];
    const float* W3 = (const float*)d_in[8];
    const float* b3 = (const float*)d_in[9];
    const float* Wm = (const float*)d_in[10];
    const float* bm = (const float*)d_in[11];
    float* out = (float*)d_out;

    char* ws = (char*)d_ws;
    int*   degc   = (int*)(ws + 0);            // 512 KB
    float* dis    = (float*)(ws + 524288);     // 512 KB
    float* invdeg = (float*)(ws + 1048576);    // 512 KB
    int*   pos_gm = (int*)(ws + 1572864);      // 512 KB + 4 (reserve 528384)
    int*   cur    = (int*)(ws + 2101248);      // 512 KB
    float* A      = (float*)(ws + 2625536);    // 32 KB
    u16*   Wt     = (u16*)(ws + 2658304);      // 32 KB
    int2*  nme    = (int2*)(ws + 2691072);     // 8 MB
    float* zp     = (float*)(ws + 11079680);   // 16.8 MB
    u16*   xy     = (u16*)(ws + 27856896);     // 67 MB

    k_zero<<<dim3(GN / 256), dim3(256), 0, stream>>>(degc);
    k_count<<<dim3(GE / 256), dim3(256), 0, stream>>>(ei, degc);
    k_scan<<<dim3(Gg), dim3(256), 0, stream>>>(degc, pos_gm, cur, dis, invdeg);
    k_scatter<<<dim3(GE / 256), dim3(256), 0, stream>>>(ei, dis, cur, nme);
    k_trans<<<dim3(64), dim3(256), 0, stream>>>(Wm, Wt);
    k_A<<<dim3(Gg), dim3(128), 0, stream>>>(x, center, invdeg, pos_gm, nme, W1, b1, Wm, bm, A);
    k_masky<<<dim3(512), dim3(256), 0, stream>>>(x, Wt, A, xy);
    k_propx<<<dim3(1024), dim3(256), 0, stream>>>(xy, invdeg, pos_gm, nme, zp);
    k_reduce<<<dim3(Nn - 1), dim3(256), 0, stream>>>(zp, W2, b2, W3, b3, out);
}

// Round 6
// 335.791 us; speedup vs baseline: 1.0723x; 1.0723x over previous
//
#include <hip/hip_runtime.h>

typedef unsigned short u16;
typedef unsigned int uint32;
typedef __bf16 bf16x8 __attribute__((ext_vector_type(8)));
typedef float f32x4 __attribute__((ext_vector_type(4)));

static constexpr int Gg = 64;
static constexpr int Nn = 2048;
static constexpr int Ee = 16384;
static constexpr int GN = Gg * Nn;   // 131072
static constexpr int GE = Gg * Ee;   // 1048576

__device__ __forceinline__ u16 f2u(float f) {  // round-to-nearest-even bf16
    uint32 i = __float_as_uint(f);
    uint32 r = (i + 0x7FFFu + ((i >> 16) & 1u)) >> 16;
    return (u16)r;
}
__device__ __forceinline__ float lo16f(uint32 v) { return __uint_as_float(v << 16); }
__device__ __forceinline__ float hi16f(uint32 v) { return __uint_as_float(v & 0xffff0000u); }

// ---------------- setup kernels ----------------

__global__ void k_zero(int* __restrict__ p) {
    p[blockIdx.x * 256 + threadIdx.x] = 0;
}

__global__ void k_count(const int* __restrict__ ei, int* __restrict__ deg) {
    int e = blockIdx.x * 256 + threadIdx.x;
    atomicAdd(&deg[ei[GE + e]], 1);   // row 1 = dst (global ids)
}

__global__ void k_dis(const int* __restrict__ deg, float* __restrict__ dis,
                      float* __restrict__ invdeg) {
    int gid = blockIdx.x * 256 + threadIdx.x;
    float d = 1.0f + (float)deg[gid];
    dis[gid] = rsqrtf(d);
    invdeg[gid] = 1.0f / d;
}

// per-group (8 graphs) exclusive scan over nodes -> pos_pn[p][i] (absolute, base p<<17)
__global__ void k_scan_p(const int* __restrict__ deg, int* __restrict__ pos_pn) {
    int p = blockIdx.x, t = threadIdx.x;   // 1024 threads, 2 nodes each
    int i0 = 2 * t, i1 = 2 * t + 1;
    int c0 = 0, c1 = 0;
    #pragma unroll
    for (int g8 = 0; g8 < 8; ++g8) {
        int g = p * 8 + g8;
        c0 += deg[(g << 11) + i0];
        c1 += deg[(g << 11) + i1];
    }
    __shared__ int ps[1024];
    ps[t] = c0 + c1; __syncthreads();
    for (int off = 1; off < 1024; off <<= 1) {
        int v = (t >= off) ? ps[t - off] : 0;
        __syncthreads();
        ps[t] += v;
        __syncthreads();
    }
    int base = (p << 17) + ps[t] - (c0 + c1);
    pos_pn[p * 2049 + i0] = base;
    pos_pn[p * 2049 + i1] = base + c0;
    if (t == 1023) pos_pn[p * 2049 + 2048] = (p + 1) << 17;
}

// deterministic per-(g,i) starts within the (p,i) bucket; two copies (cur is consumed)
__global__ void k_start(const int* __restrict__ deg, const int* __restrict__ pos_pn,
                        int* __restrict__ gstart, int* __restrict__ cur) {
    int i = blockIdx.x * 256 + threadIdx.x;   // node 0..2047
    #pragma unroll
    for (int p = 0; p < 8; ++p) {
        int run = pos_pn[p * 2049 + i];
        #pragma unroll
        for (int g8 = 0; g8 < 8; ++g8) {
            int g = p * 8 + g8;
            gstart[(g << 11) + i] = run;
            cur[(g << 11) + i] = run;
            run += deg[(g << 11) + i];
        }
    }
}

// rank-within-(g,i) atomic: 131072 cursors, ~8 collisions each
__global__ void k_scatter(const int* __restrict__ ei, const float* __restrict__ dis,
                          int* __restrict__ cur, int2* __restrict__ nme) {
    int e = blockIdx.x * 256 + threadIdx.x;
    int s = ei[e];          // src gid
    int d = ei[GE + e];     // dst gid
    int p = atomicAdd(&cur[d], 1);
    nme[p] = make_int2(s, __float_as_int(dis[s] * dis[d]));
}

// transpose bottom half of Wm -> Wt[c][f] bf16
__global__ void k_trans(const float* __restrict__ Wm, u16* __restrict__ Wt) {
    int idx = blockIdx.x * 256 + threadIdx.x;   // 16384
    int f = idx >> 7, c = idx & 127;
    Wt[c * 128 + f] = f2u(Wm[(128 + f) * 128 + c]);
}

// A[g] = (ce @ Wm_top) + bm, ce = (x[center]*invdeg + incident edges) @ W1 + b1
__global__ void k_A(const float* __restrict__ x, const int* __restrict__ center,
                    const float* __restrict__ invdeg, const int* __restrict__ gstart,
                    const int* __restrict__ deg, const int2* __restrict__ nme,
                    const float* __restrict__ W1, const float* __restrict__ b1,
                    const float* __restrict__ Wm, const float* __restrict__ bm,
                    float* __restrict__ A) {
    int g = blockIdx.x, t = threadIdx.x;   // 128 threads
    __shared__ float cepre[128], ce[128];
    int cg = (g << 11) + center[g];
    float v = x[cg * 128 + t] * invdeg[cg];
    int p0 = gstart[cg], p1 = p0 + deg[cg];
    for (int e = p0; e < p1; ++e) {          // usually empty (center has no in-edges)
        int2 m = nme[e];
        v += __int_as_float(m.y) * x[m.x * 128 + t];
    }
    cepre[t] = v; __syncthreads();
    float a = b1[t];
    #pragma unroll 8
    for (int f = 0; f < 128; ++f) a += cepre[f] * W1[f * 128 + t];
    ce[t] = a; __syncthreads();
    float o = bm[t];
    #pragma unroll 8
    for (int h = 0; h < 128; ++h) o += ce[h] * Wm[h * 128 + t];
    A[g * 128 + t] = o;
}

// ---------------- mask + y GEMM (MFMA), persistent blocks, packed xy ----------------
// xy row (256 u16): group k (u16[4k..4k+4)) = { y[2k], y[2k+1], x[2k], x[2k+1] } bf16
__global__ __launch_bounds__(256) void k_masky(const float* __restrict__ x,
                                               const u16* __restrict__ Wt,
                                               const float* __restrict__ A,
                                               u16* __restrict__ xy) {
    __shared__ u16 sWt[16384];
    __shared__ float sA[128];
    __shared__ float sC[4][2048];
    int t = threadIdx.x;
    #pragma unroll
    for (int j = 0; j < 8; ++j)
        ((uint4*)sWt)[j * 256 + t] = ((const uint4*)Wt)[j * 256 + t];

    int w = t >> 6, l = t & 63;
    int lm = l & 15, lq = l >> 4;

    for (int tile = blockIdx.x; tile < 2048; tile += 512) {
        int g = tile >> 5;
        __syncthreads();                       // covers sWt (1st iter) + sA reuse
        if (t < 128) sA[t] = A[g * 128 + t];
        __syncthreads();

        int row0 = tile * 64 + w * 16;
        f32x4 acc[8] = {};
        #pragma unroll
        for (int ks = 0; ks < 4; ++ks) {
            const float* xp = x + (row0 + lm) * 128 + ks * 32 + lq * 8;
            float4 x0 = *(const float4*)(xp);
            float4 x1 = *(const float4*)(xp + 4);
            union { u16 u[8]; bf16x8 v; } af;
            af.u[0] = f2u(x0.x); af.u[1] = f2u(x0.y); af.u[2] = f2u(x0.z); af.u[3] = f2u(x0.w);
            af.u[4] = f2u(x1.x); af.u[5] = f2u(x1.y); af.u[6] = f2u(x1.z); af.u[7] = f2u(x1.w);
            #pragma unroll
            for (int ct = 0; ct < 8; ++ct) {
                bf16x8 b = *reinterpret_cast<const bf16x8*>(sWt + (ct * 16 + lm) * 128 + ks * 32 + lq * 8);
                acc[ct] = __builtin_amdgcn_mfma_f32_16x16x32_bf16(af.v, b, acc[ct], 0, 0, 0);
            }
        }

        // per-wave C tile: wave-internal LDS round-trip, no block barrier needed
        float* myC = sC[w];
        #pragma unroll
        for (int ct = 0; ct < 8; ++ct)
            #pragma unroll
            for (int r = 0; r < 4; ++r)
                myC[(lq * 4 + r) * 128 + ct * 16 + lm] = acc[ct][r];

        int lr = l >> 2;
        int cc = (l & 3) * 32;
        int grow = row0 + lr;
        const float* xr = x + grow * 128 + cc;
        u16* orow = xy + grow * 256;
        #pragma unroll
        for (int j = 0; j < 4; ++j) {
            int c0 = cc + j * 8;
            float4 ca = *(const float4*)(myC + lr * 128 + c0);
            float4 cb = *(const float4*)(myC + lr * 128 + c0 + 4);
            float4 xa = *(const float4*)(xr + j * 8);
            float4 xd = *(const float4*)(xr + j * 8 + 4);
            float m0 = fmaxf(ca.x + sA[c0 + 0], 0.f) * xa.x;
            float m1 = fmaxf(ca.y + sA[c0 + 1], 0.f) * xa.y;
            float m2 = fmaxf(ca.z + sA[c0 + 2], 0.f) * xa.z;
            float m3 = fmaxf(ca.w + sA[c0 + 3], 0.f) * xa.w;
            float m4 = fmaxf(cb.x + sA[c0 + 4], 0.f) * xd.x;
            float m5 = fmaxf(cb.y + sA[c0 + 5], 0.f) * xd.y;
            float m6 = fmaxf(cb.z + sA[c0 + 6], 0.f) * xd.z;
            float m7 = fmaxf(cb.w + sA[c0 + 7], 0.f) * xd.w;
            uint4 q1, q2;
            q1.x = (uint32)f2u(m0) | ((uint32)f2u(m1) << 16);
            q1.y = (uint32)f2u(xa.x) | ((uint32)f2u(xa.y) << 16);
            q1.z = (uint32)f2u(m2) | ((uint32)f2u(m3) << 16);
            q1.w = (uint32)f2u(xa.z) | ((uint32)f2u(xa.w) << 16);
            q2.x = (uint32)f2u(m4) | ((uint32)f2u(m5) << 16);
            q2.y = (uint32)f2u(xd.x) | ((uint32)f2u(xd.y) << 16);
            q2.z = (uint32)f2u(m6) | ((uint32)f2u(m7) << 16);
            q2.w = (uint32)f2u(xd.z) | ((uint32)f2u(xd.w) << 16);
            *(uint4*)(orow + 2 * c0) = q1;
            *(uint4*)(orow + 2 * c0 + 8) = q2;
        }
    }
}

// ---------------- propagation: (p,i)-bucketed contiguous streams ----------------
// blockIdx = p + 8*c : group p -> XCD p (heuristic), c = 8-node chunk (0..255).
// Wave handles 2 nodes; each node = one contiguous ~64-entry stream, 4-deep.
__global__ __launch_bounds__(256) void k_propx(const u16* __restrict__ xy,
                                               const float* __restrict__ invdeg,
                                               const int* __restrict__ pos_pn,
                                               const int2* __restrict__ nme,
                                               float* __restrict__ zp) {
    int b = blockIdx.x;
    int p = b & 7, c = b >> 3;
    int t = threadIdx.x, w = t >> 6, l = t & 63;
    int col = 4 * l;
    int ibase = c * 8 + w * 2;
    #pragma unroll
    for (int d = 0; d < 2; ++d) {
        int i = ibase + d;
        float aY0 = 0.f, aY1 = 0.f, aX0 = 0.f, aX1 = 0.f;
        // self terms: 8 graphs of the group, independent loads
        #pragma unroll
        for (int g8 = 0; g8 < 8; ++g8) {
            int gid = ((p * 8 + g8) << 11) + i;
            float cf = invdeg[gid];
            uint2 v = *(const uint2*)(xy + gid * 256 + col);
            aY0 += cf * lo16f(v.x); aY1 += cf * hi16f(v.x);
            aX0 += cf * lo16f(v.y); aX1 += cf * hi16f(v.y);
        }
        // edge stream: contiguous bucket, graph-ordered
        int j = pos_pn[p * 2049 + i], jend = pos_pn[p * 2049 + i + 1];
        if ((j & 1) && j < jend) {            // fix parity for aligned int4 meta loads
            int2 m = nme[j];
            uint2 v = *(const uint2*)(xy + m.x * 256 + col);
            float cf = __int_as_float(m.y);
            aY0 += cf * lo16f(v.x); aY1 += cf * hi16f(v.x);
            aX0 += cf * lo16f(v.y); aX1 += cf * hi16f(v.y);
            ++j;
        }
        for (; j + 3 < jend; j += 4) {
            int4 ma = *(const int4*)(nme + j);
            int4 mb = *(const int4*)(nme + j + 2);
            uint2 v0 = *(const uint2*)(xy + ma.x * 256 + col);
            uint2 v1 = *(const uint2*)(xy + ma.z * 256 + col);
            uint2 v2 = *(const uint2*)(xy + mb.x * 256 + col);
            uint2 v3 = *(const uint2*)(xy + mb.z * 256 + col);
            float c0 = __int_as_float(ma.y), c1 = __int_as_float(ma.w);
            float c2 = __int_as_float(mb.y), c3 = __int_as_float(mb.w);
            aY0 += c0 * lo16f(v0.x) + c1 * lo16f(v1.x) + c2 * lo16f(v2.x) + c3 * lo16f(v3.x);
            aY1 += c0 * hi16f(v0.x) + c1 * hi16f(v1.x) + c2 * hi16f(v2.x) + c3 * hi16f(v3.x);
            aX0 += c0 * lo16f(v0.y) + c1 * lo16f(v1.y) + c2 * lo16f(v2.y) + c3 * lo16f(v3.y);
            aX1 += c0 * hi16f(v0.y) + c1 * hi16f(v1.y) + c2 * hi16f(v2.y) + c3 * hi16f(v3.y);
        }
        for (; j < jend; ++j) {
            int2 m = nme[j];
            uint2 v = *(const uint2*)(xy + m.x * 256 + col);
            float cf = __int_as_float(m.y);
            aY0 += cf * lo16f(v.x); aY1 += cf * hi16f(v.x);
            aX0 += cf * lo16f(v.y); aX1 += cf * hi16f(v.y);
        }
        *(float4*)(zp + (((p << 11) + i) << 8) + col) = make_float4(aY0, aY1, aX0, aX1);
    }
}

// ---------------- reduce partials + fused output matvecs ----------------
__global__ __launch_bounds__(256) void k_reduce(const float* __restrict__ zp,
                                                const float* __restrict__ W2, const float* __restrict__ b2,
                                                const float* __restrict__ W3, const float* __restrict__ b3,
                                                float* __restrict__ out) {
    int i = blockIdx.x;   // node 0..2046
    int t = threadIdx.x;
    __shared__ float zm[128], zxm[128];
    float s = 0.f;
    #pragma unroll
    for (int p = 0; p < 8; ++p) s += zp[(((p << 11) + i) << 8) + t];
    s *= (1.0f / 64.0f);
    int k = t >> 2, r = t & 3;
    if (r < 2) zm[2 * k + r] = s; else zxm[2 * k + (r - 2)] = s;
    __syncthreads();
    int cc = t & 127;
    if (t < 128) {
        float acc = b2[cc];
        #pragma unroll 8
        for (int f = 0; f < 128; ++f) acc += zm[f] * W2[f * 128 + cc];
        out[i * 128 + cc] = acc;
    } else {
        float acc = b3[cc];
        #pragma unroll 8
        for (int f = 0; f < 128; ++f) acc += (zxm[f] - zm[f]) * W3[f * 128 + cc];
        out[2047 * 128 + i * 128 + cc] = acc;
    }
}

// ---------------- launch ----------------

extern "C" void kernel_launch(void* const* d_in, const int* in_sizes, int n_in,
                              void* d_out, int out_size, void* d_ws, size_t ws_size,
                              hipStream_t stream) {
    const float* x    = (const float*)d_in[0];
    const int* ei     = (const int*)d_in[1];
    const int* center = (const int*)d_in[3];
    const float* W1 = (const float*)d_in[4];
    const float* b1 = (const float*)d_in[5];
    const float* W2 = (const float*)d_in[6];
    const float* b2 = (const float*)d_in[7];
    const float* W3 = (const float*)d_in[8];
    const float* b3 = (const float*)d_in[9];
    const float* Wm = (const float*)d_in[10];
    const float* bm = (const float*)d_in[11];
    float* out = (float*)d_out;

    char* ws = (char*)d_ws;
    int*   degc   = (int*)(ws + 0);            // 512 KB
    float* dis    = (float*)(ws + 524288);     // 512 KB
    float* invdeg = (float*)(ws + 1048576);    // 512 KB
    int*   pos_pn = (int*)(ws + 1572864);      // 8*2049*4 = 65568 B (reserve 66560)
    int*   gstart = (int*)(ws + 1639424);      // 512 KB
    int*   cur    = (int*)(ws + 2163712);      // 512 KB
    float* A      = (float*)(ws + 2688000);    // 32 KB
    u16*   Wt     = (u16*)(ws + 2720768);      // 32 KB
    int2*  nme    = (int2*)(ws + 2753536);     // 8 MB
    float* zp     = (float*)(ws + 11142144);   // 16.8 MB
    u16*   xy     = (u16*)(ws + 27919360);     // 67 MB  (total ~95 MB)

    k_zero<<<dim3(GN / 256), dim3(256), 0, stream>>>(degc);
    k_count<<<dim3(GE / 256), dim3(256), 0, stream>>>(ei, degc);
    k_dis<<<dim3(GN / 256), dim3(256), 0, stream>>>(degc, dis, invdeg);
    k_scan_p<<<dim3(8), dim3(1024), 0, stream>>>(degc, pos_pn);
    k_start<<<dim3(Nn / 256), dim3(256), 0, stream>>>(degc, pos_pn, gstart, cur);
    k_scatter<<<dim3(GE / 256), dim3(256), 0, stream>>>(ei, dis, cur, nme);
    k_trans<<<dim3(64), dim3(256), 0, stream>>>(Wm, Wt);
    k_A<<<dim3(Gg), dim3(128), 0, stream>>>(x, center, invdeg, gstart, degc, nme, W1, b1, Wm, bm, A);
    k_masky<<<dim3(512), dim3(256), 0, stream>>>(x, Wt, A, xy);
    k_propx<<<dim3(2048), dim3(256), 0, stream>>>(xy, invdeg, pos_pn, nme, zp);
    k_reduce<<<dim3(Nn - 1), dim3(256), 0, stream>>>(zp, W2, b2, W3, b3, out);
}

// Round 7
// 327.193 us; speedup vs baseline: 1.1004x; 1.0263x over previous
//
#include <hip/hip_runtime.h>

typedef unsigned short u16;
typedef unsigned int uint32;
typedef __bf16 bf16x8 __attribute__((ext_vector_type(8)));
typedef float f32x4 __attribute__((ext_vector_type(4)));

static constexpr int Gg = 64;
static constexpr int Nn = 2048;
static constexpr int Ee = 16384;
static constexpr int GN = Gg * Nn;   // 131072
static constexpr int GE = Gg * Ee;   // 1048576

__device__ __forceinline__ u16 f2u(float f) {  // round-to-nearest-even bf16
    uint32 i = __float_as_uint(f);
    uint32 r = (i + 0x7FFFu + ((i >> 16) & 1u)) >> 16;
    return (u16)r;
}
__device__ __forceinline__ float lo16f(uint32 v) { return __uint_as_float(v << 16); }
__device__ __forceinline__ float hi16f(uint32 v) { return __uint_as_float(v & 0xffff0000u); }

// ---------------- setup kernels ----------------

__global__ void k_count(const int* __restrict__ ei, int* __restrict__ deg) {
    int e = blockIdx.x * 256 + threadIdx.x;
    atomicAdd(&deg[ei[GE + e]], 1);   // row 1 = dst (global ids)
}

__global__ void k_dis(const int* __restrict__ deg, float* __restrict__ dis,
                      float* __restrict__ invdeg) {
    int gid = blockIdx.x * 256 + threadIdx.x;
    float d = 1.0f + (float)deg[gid];
    dis[gid] = rsqrtf(d);
    invdeg[gid] = 1.0f / d;
}

// per-group (8 graphs) exclusive scan over nodes -> pos_pn[p][i] (absolute, base p<<17)
__global__ void k_scan_p(const int* __restrict__ deg, int* __restrict__ pos_pn) {
    int p = blockIdx.x, t = threadIdx.x;   // 1024 threads, 2 nodes each
    int i0 = 2 * t, i1 = 2 * t + 1;
    int c0 = 0, c1 = 0;
    #pragma unroll
    for (int g8 = 0; g8 < 8; ++g8) {
        int g = p * 8 + g8;
        c0 += deg[(g << 11) + i0];
        c1 += deg[(g << 11) + i1];
    }
    __shared__ int ps[1024];
    ps[t] = c0 + c1; __syncthreads();
    for (int off = 1; off < 1024; off <<= 1) {
        int v = (t >= off) ? ps[t - off] : 0;
        __syncthreads();
        ps[t] += v;
        __syncthreads();
    }
    int base = (p << 17) + ps[t] - (c0 + c1);
    pos_pn[p * 2049 + i0] = base;
    pos_pn[p * 2049 + i1] = base + c0;
    if (t == 1023) pos_pn[p * 2049 + 2048] = (p + 1) << 17;
}

// deterministic per-(g,i) starts within the (p,i) bucket; two copies (cur is consumed)
__global__ void k_start(const int* __restrict__ deg, const int* __restrict__ pos_pn,
                        int* __restrict__ gstart, int* __restrict__ cur) {
    int i = blockIdx.x * 256 + threadIdx.x;   // node 0..2047
    #pragma unroll
    for (int p = 0; p < 8; ++p) {
        int run = pos_pn[p * 2049 + i];
        #pragma unroll
        for (int g8 = 0; g8 < 8; ++g8) {
            int g = p * 8 + g8;
            gstart[(g << 11) + i] = run;
            cur[(g << 11) + i] = run;
            run += deg[(g << 11) + i];
        }
    }
}

// rank-within-(g,i) atomic: 131072 cursors, ~8 collisions each
__global__ void k_scatter(const int* __restrict__ ei, const float* __restrict__ dis,
                          int* __restrict__ cur, int2* __restrict__ nme) {
    int e = blockIdx.x * 256 + threadIdx.x;
    int s = ei[e];          // src gid
    int d = ei[GE + e];     // dst gid
    int p = atomicAdd(&cur[d], 1);
    nme[p] = make_int2(s, __float_as_int(dis[s] * dis[d]));
}

// transpose bottom half of Wm -> Wt[c][f] bf16
__global__ void k_trans(const float* __restrict__ Wm, u16* __restrict__ Wt) {
    int idx = blockIdx.x * 256 + threadIdx.x;   // 16384
    int f = idx >> 7, c = idx & 127;
    Wt[c * 128 + f] = f2u(Wm[(128 + f) * 128 + c]);
}

// A[g] = (ce @ Wm_top) + bm, ce = (x[center]*invdeg + incident edges) @ W1 + b1
__global__ void k_A(const float* __restrict__ x, const int* __restrict__ center,
                    const float* __restrict__ invdeg, const int* __restrict__ gstart,
                    const int* __restrict__ deg, const int2* __restrict__ nme,
                    const float* __restrict__ W1, const float* __restrict__ b1,
                    const float* __restrict__ Wm, const float* __restrict__ bm,
                    float* __restrict__ A) {
    int g = blockIdx.x, t = threadIdx.x;   // 128 threads
    __shared__ float cepre[128], ce[128];
    int cg = (g << 11) + center[g];
    float v = x[cg * 128 + t] * invdeg[cg];
    int p0 = gstart[cg], p1 = p0 + deg[cg];
    for (int e = p0; e < p1; ++e) {          // usually empty (center has no in-edges)
        int2 m = nme[e];
        v += __int_as_float(m.y) * x[m.x * 128 + t];
    }
    cepre[t] = v; __syncthreads();
    float a = b1[t];
    #pragma unroll 8
    for (int f = 0; f < 128; ++f) a += cepre[f] * W1[f * 128 + t];
    ce[t] = a; __syncthreads();
    float o = bm[t];
    #pragma unroll 8
    for (int h = 0; h < 128; ++h) o += ce[h] * Wm[h * 128 + t];
    A[g * 128 + t] = o;
}

// ---------------- mask + y GEMM (MFMA), persistent blocks, packed xy ----------------
// xy row (256 u16): group k (u16[4k..4k+4)) = { y[2k], y[2k+1], x[2k], x[2k+1] } bf16
__global__ __launch_bounds__(256) void k_masky(const float* __restrict__ x,
                                               const u16* __restrict__ Wt,
                                               const float* __restrict__ A,
                                               u16* __restrict__ xy) {
    __shared__ u16 sWt[16384];
    __shared__ float sA[128];
    __shared__ float sC[4][2048];
    int t = threadIdx.x;
    #pragma unroll
    for (int j = 0; j < 8; ++j)
        ((uint4*)sWt)[j * 256 + t] = ((const uint4*)Wt)[j * 256 + t];

    int w = t >> 6, l = t & 63;
    int lm = l & 15, lq = l >> 4;

    for (int tile = blockIdx.x; tile < 2048; tile += 512) {
        int g = tile >> 5;
        __syncthreads();                       // covers sWt (1st iter) + sA reuse
        if (t < 128) sA[t] = A[g * 128 + t];
        __syncthreads();

        int row0 = tile * 64 + w * 16;
        f32x4 acc[8] = {};
        #pragma unroll
        for (int ks = 0; ks < 4; ++ks) {
            const float* xp = x + (row0 + lm) * 128 + ks * 32 + lq * 8;
            float4 x0 = *(const float4*)(xp);
            float4 x1 = *(const float4*)(xp + 4);
            union { u16 u[8]; bf16x8 v; } af;
            af.u[0] = f2u(x0.x); af.u[1] = f2u(x0.y); af.u[2] = f2u(x0.z); af.u[3] = f2u(x0.w);
            af.u[4] = f2u(x1.x); af.u[5] = f2u(x1.y); af.u[6] = f2u(x1.z); af.u[7] = f2u(x1.w);
            #pragma unroll
            for (int ct = 0; ct < 8; ++ct) {
                bf16x8 b = *reinterpret_cast<const bf16x8*>(sWt + (ct * 16 + lm) * 128 + ks * 32 + lq * 8);
                acc[ct] = __builtin_amdgcn_mfma_f32_16x16x32_bf16(af.v, b, acc[ct], 0, 0, 0);
            }
        }

        // per-wave C tile: wave-internal LDS round-trip, no block barrier needed
        float* myC = sC[w];
        #pragma unroll
        for (int ct = 0; ct < 8; ++ct)
            #pragma unroll
            for (int r = 0; r < 4; ++r)
                myC[(lq * 4 + r) * 128 + ct * 16 + lm] = acc[ct][r];

        int lr = l >> 2;
        int cc = (l & 3) * 32;
        int grow = row0 + lr;
        const float* xr = x + grow * 128 + cc;
        u16* orow = xy + grow * 256;
        #pragma unroll
        for (int j = 0; j < 4; ++j) {
            int c0 = cc + j * 8;
            float4 ca = *(const float4*)(myC + lr * 128 + c0);
            float4 cb = *(const float4*)(myC + lr * 128 + c0 + 4);
            float4 xa = *(const float4*)(xr + j * 8);
            float4 xd = *(const float4*)(xr + j * 8 + 4);
            float m0 = fmaxf(ca.x + sA[c0 + 0], 0.f) * xa.x;
            float m1 = fmaxf(ca.y + sA[c0 + 1], 0.f) * xa.y;
            float m2 = fmaxf(ca.z + sA[c0 + 2], 0.f) * xa.z;
            float m3 = fmaxf(ca.w + sA[c0 + 3], 0.f) * xa.w;
            float m4 = fmaxf(cb.x + sA[c0 + 4], 0.f) * xd.x;
            float m5 = fmaxf(cb.y + sA[c0 + 5], 0.f) * xd.y;
            float m6 = fmaxf(cb.z + sA[c0 + 6], 0.f) * xd.z;
            float m7 = fmaxf(cb.w + sA[c0 + 7], 0.f) * xd.w;
            uint4 q1, q2;
            q1.x = (uint32)f2u(m0) | ((uint32)f2u(m1) << 16);
            q1.y = (uint32)f2u(xa.x) | ((uint32)f2u(xa.y) << 16);
            q1.z = (uint32)f2u(m2) | ((uint32)f2u(m3) << 16);
            q1.w = (uint32)f2u(xa.z) | ((uint32)f2u(xa.w) << 16);
            q2.x = (uint32)f2u(m4) | ((uint32)f2u(m5) << 16);
            q2.y = (uint32)f2u(xd.x) | ((uint32)f2u(xd.y) << 16);
            q2.z = (uint32)f2u(m6) | ((uint32)f2u(m7) << 16);
            q2.w = (uint32)f2u(xd.z) | ((uint32)f2u(xd.w) << 16);
            *(uint4*)(orow + 2 * c0) = q1;
            *(uint4*)(orow + 2 * c0 + 8) = q2;
        }
    }
}

// ---------------- propagation: half-wave row mapping, 2 rows per load ----------------
// blockIdx = p + 8*c : group p -> XCD p (heuristic), c = 4-node chunk (0..511).
// Wave = one node's stream; lanes 0-31 process even-offset entries, 32-63 odd.
#define ACC8(v, cf)                                                     \
    aY0 += (cf) * lo16f((v).x); aY1 += (cf) * hi16f((v).x);             \
    aX0 += (cf) * lo16f((v).y); aX1 += (cf) * hi16f((v).y);             \
    aY2 += (cf) * lo16f((v).z); aY3 += (cf) * hi16f((v).z);             \
    aX2 += (cf) * lo16f((v).w); aX3 += (cf) * hi16f((v).w);

__global__ __launch_bounds__(256) void k_propx(const u16* __restrict__ xy,
                                               const float* __restrict__ invdeg,
                                               const int* __restrict__ pos_pn,
                                               const int2* __restrict__ nme,
                                               float* __restrict__ zp) {
    int b = blockIdx.x;
    int p = b & 7, c = b >> 3;
    int t = threadIdx.x, w = t >> 6, l = t & 63;
    int half = l >> 5, cl = l & 31;
    int i = c * 4 + w;
    float aY0 = 0.f, aY1 = 0.f, aY2 = 0.f, aY3 = 0.f;
    float aX0 = 0.f, aX1 = 0.f, aX2 = 0.f, aX3 = 0.f;

    // self terms: 8 graphs, 2 rows per load
    #pragma unroll
    for (int k = 0; k < 4; ++k) {
        int gid = ((p * 8 + 2 * k + half) << 11) + i;
        float cf = invdeg[gid];
        uint4 v = *(const uint4*)(xy + gid * 256 + cl * 8);
        ACC8(v, cf)
    }

    // edge stream: contiguous (p,i) bucket; 8 entries/iter, 4 row-loads in flight
    int j = pos_pn[p * 2049 + i], jend = pos_pn[p * 2049 + i + 1];
    for (; j + 7 < jend; j += 8) {
        int2 m0 = nme[j + half];
        int2 m1 = nme[j + 2 + half];
        int2 m2 = nme[j + 4 + half];
        int2 m3 = nme[j + 6 + half];
        uint4 v0 = *(const uint4*)(xy + m0.x * 256 + cl * 8);
        uint4 v1 = *(const uint4*)(xy + m1.x * 256 + cl * 8);
        uint4 v2 = *(const uint4*)(xy + m2.x * 256 + cl * 8);
        uint4 v3 = *(const uint4*)(xy + m3.x * 256 + cl * 8);
        float c0 = __int_as_float(m0.y), c1 = __int_as_float(m1.y);
        float c2 = __int_as_float(m2.y), c3 = __int_as_float(m3.y);
        ACC8(v0, c0) ACC8(v1, c1) ACC8(v2, c2) ACC8(v3, c3)
    }
    for (; j < jend; j += 2) {
        int idx = j + half;
        if (idx < jend) {
            int2 m = nme[idx];
            uint4 v = *(const uint4*)(xy + m.x * 256 + cl * 8);
            float cf = __int_as_float(m.y);
            ACC8(v, cf)
        }
    }

    // combine halves (each col-block is split across lanes l and l^32)
    aY0 += __shfl_xor(aY0, 32, 64); aY1 += __shfl_xor(aY1, 32, 64);
    aX0 += __shfl_xor(aX0, 32, 64); aX1 += __shfl_xor(aX1, 32, 64);
    aY2 += __shfl_xor(aY2, 32, 64); aY3 += __shfl_xor(aY3, 32, 64);
    aX2 += __shfl_xor(aX2, 32, 64); aX3 += __shfl_xor(aX3, 32, 64);
    if (half == 0) {
        float* zr = zp + (((p << 11) + i) << 8) + cl * 8;
        *(float4*)(zr) = make_float4(aY0, aY1, aX0, aX1);
        *(float4*)(zr + 4) = make_float4(aY2, aY3, aX2, aX3);
    }
}

// ---------------- reduce partials + fused output matvecs ----------------
__global__ __launch_bounds__(256) void k_reduce(const float* __restrict__ zp,
                                                const float* __restrict__ W2, const float* __restrict__ b2,
                                                const float* __restrict__ W3, const float* __restrict__ b3,
                                                float* __restrict__ out) {
    int i = blockIdx.x;   // node 0..2046
    int t = threadIdx.x;
    __shared__ float zm[128], zxm[128];
    float s = 0.f;
    #pragma unroll
    for (int p = 0; p < 8; ++p) s += zp[(((p << 11) + i) << 8) + t];
    s *= (1.0f / 64.0f);
    int k = t >> 2, r = t & 3;
    if (r < 2) zm[2 * k + r] = s; else zxm[2 * k + (r - 2)] = s;
    __syncthreads();
    int cc = t & 127;
    if (t < 128) {
        float acc = b2[cc];
        #pragma unroll 8
        for (int f = 0; f < 128; ++f) acc += zm[f] * W2[f * 128 + cc];
        out[i * 128 + cc] = acc;
    } else {
        float acc = b3[cc];
        #pragma unroll 8
        for (int f = 0; f < 128; ++f) acc += (zxm[f] - zm[f]) * W3[f * 128 + cc];
        out[2047 * 128 + i * 128 + cc] = acc;
    }
}

// ---------------- launch ----------------

extern "C" void kernel_launch(void* const* d_in, const int* in_sizes, int n_in,
                              void* d_out, int out_size, void* d_ws, size_t ws_size,
                              hipStream_t stream) {
    const float* x    = (const float*)d_in[0];
    const int* ei     = (const int*)d_in[1];
    const int* center = (const int*)d_in[3];
    const float* W1 = (const float*)d_in[4];
    const float* b1 = (const float*)d_in[5];
    const float* W2 = (const float*)d_in[6];
    const float* b2 = (const float*)d_in[7];
    const float* W3 = (const float*)d_in[8];
    const float* b3 = (const float*)d_in[9];
    const float* Wm = (const float*)d_in[10];
    const float* bm = (const float*)d_in[11];
    float* out = (float*)d_out;

    char* ws = (char*)d_ws;
    int*   degc   = (int*)(ws + 0);            // 512 KB
    float* dis    = (float*)(ws + 524288);     // 512 KB
    float* invdeg = (float*)(ws + 1048576);    // 512 KB
    int*   pos_pn = (int*)(ws + 1572864);      // 8*2049*4 = 65568 B (reserve 66560)
    int*   gstart = (int*)(ws + 1639424);      // 512 KB
    int*   cur    = (int*)(ws + 2163712);      // 512 KB
    float* A      = (float*)(ws + 2688000);    // 32 KB
    u16*   Wt     = (u16*)(ws + 2720768);      // 32 KB
    int2*  nme    = (int2*)(ws + 2753536);     // 8 MB
    float* zp     = (float*)(ws + 11142144);   // 16.8 MB
    u16*   xy     = (u16*)(ws + 27919360);     // 67 MB  (total ~95 MB)

    hipMemsetAsync(degc, 0, GN * sizeof(int), stream);
    k_count<<<dim3(GE / 256), dim3(256), 0, stream>>>(ei, degc);
    k_dis<<<dim3(GN / 256), dim3(256), 0, stream>>>(degc, dis, invdeg);
    k_scan_p<<<dim3(8), dim3(1024), 0, stream>>>(degc, pos_pn);
    k_start<<<dim3(Nn / 256), dim3(256), 0, stream>>>(degc, pos_pn, gstart, cur);
    k_scatter<<<dim3(GE / 256), dim3(256), 0, stream>>>(ei, dis, cur, nme);
    k_trans<<<dim3(64), dim3(256), 0, stream>>>(Wm, Wt);
    k_A<<<dim3(Gg), dim3(128), 0, stream>>>(x, center, invdeg, gstart, degc, nme, W1, b1, Wm, bm, A);
    k_masky<<<dim3(512), dim3(256), 0, stream>>>(x, Wt, A, xy);
    k_propx<<<dim3(4096), dim3(256), 0, stream>>>(xy, invdeg, pos_pn, nme, zp);
    k_reduce<<<dim3(Nn - 1), dim3(256), 0, stream>>>(zp, W2, b2, W3, b3, out);
}

// Round 8
// 276.266 us; speedup vs baseline: 1.3033x; 1.1843x over previous
//
#include <hip/hip_runtime.h>

typedef unsigned short u16;
typedef unsigned int uint32;
typedef __bf16 bf16x8 __attribute__((ext_vector_type(8)));
typedef float f32x4 __attribute__((ext_vector_type(4)));

static constexpr int Gg = 64;
static constexpr int Nn = 2048;
static constexpr int Ee = 16384;
static constexpr int GN = Gg * Nn;   // 131072
static constexpr int GE = Gg * Ee;   // 1048576

__device__ __forceinline__ u16 f2u(float f) {  // round-to-nearest-even bf16
    uint32 i = __float_as_uint(f);
    uint32 r = (i + 0x7FFFu + ((i >> 16) & 1u)) >> 16;
    return (u16)r;
}
__device__ __forceinline__ float lo16f(uint32 v) { return __uint_as_float(v << 16); }
__device__ __forceinline__ float hi16f(uint32 v) { return __uint_as_float(v & 0xffff0000u); }

// ---------------- setup kernels ----------------

// per-graph LDS histogram of dst -> degc, dis, invdeg (no global atomics)
__global__ __launch_bounds__(1024) void k_hist(const int* __restrict__ ei, int* __restrict__ deg,
                                               float* __restrict__ dis, float* __restrict__ invdeg) {
    int g = blockIdx.x, t = threadIdx.x;
    __shared__ int h[2048];
    h[t] = 0; h[t + 1024] = 0;
    __syncthreads();
    #pragma unroll
    for (int k = 0; k < 16; ++k) {
        int d = ei[GE + g * Ee + k * 1024 + t];
        atomicAdd(&h[d & (Nn - 1)], 1);
    }
    __syncthreads();
    #pragma unroll
    for (int k = 0; k < 2; ++k) {
        int i = k * 1024 + t;
        int c = h[i];
        deg[(g << 11) + i] = c;
        float dd = 1.0f + (float)c;
        dis[(g << 11) + i] = rsqrtf(dd);
        invdeg[(g << 11) + i] = 1.0f / dd;
    }
}

// per-group (8 graphs) exclusive scan over nodes -> pos_pn[p][i] (absolute, base p<<17)
__global__ void k_scan_p(const int* __restrict__ deg, int* __restrict__ pos_pn) {
    int p = blockIdx.x, t = threadIdx.x;   // 1024 threads, 2 nodes each
    int i0 = 2 * t, i1 = 2 * t + 1;
    int c0 = 0, c1 = 0;
    #pragma unroll
    for (int g8 = 0; g8 < 8; ++g8) {
        int g = p * 8 + g8;
        c0 += deg[(g << 11) + i0];
        c1 += deg[(g << 11) + i1];
    }
    __shared__ int ps[1024];
    ps[t] = c0 + c1; __syncthreads();
    for (int off = 1; off < 1024; off <<= 1) {
        int v = (t >= off) ? ps[t - off] : 0;
        __syncthreads();
        ps[t] += v;
        __syncthreads();
    }
    int base = (p << 17) + ps[t] - (c0 + c1);
    pos_pn[p * 2049 + i0] = base;
    pos_pn[p * 2049 + i1] = base + c0;
    if (t == 1023) pos_pn[p * 2049 + 2048] = (p + 1) << 17;
}

// deterministic per-(g,i) starts within the (p,i) bucket
__global__ void k_start(const int* __restrict__ deg, const int* __restrict__ pos_pn,
                        int* __restrict__ gstart) {
    int i = blockIdx.x * 256 + threadIdx.x;   // node 0..2047
    #pragma unroll
    for (int p = 0; p < 8; ++p) {
        int run = pos_pn[p * 2049 + i];
        #pragma unroll
        for (int g8 = 0; g8 < 8; ++g8) {
            int g = p * 8 + g8;
            gstart[(g << 11) + i] = run;
            run += deg[(g << 11) + i];
        }
    }
}

// per-graph scatter with LDS cursors (no global atomics)
__global__ __launch_bounds__(1024) void k_scatter(const int* __restrict__ ei, const float* __restrict__ dis,
                                                  const int* __restrict__ gstart, int2* __restrict__ nme) {
    int g = blockIdx.x, t = threadIdx.x;
    __shared__ int curs[2048];
    curs[t] = gstart[(g << 11) + t];
    curs[t + 1024] = gstart[(g << 11) + t + 1024];
    __syncthreads();
    #pragma unroll
    for (int k = 0; k < 16; ++k) {
        int e = g * Ee + k * 1024 + t;
        int s = ei[e];          // src gid
        int d = ei[GE + e];     // dst gid
        int p = atomicAdd(&curs[d & (Nn - 1)], 1);
        nme[p] = make_int2(s, __float_as_int(dis[s] * dis[d]));
    }
}

// pack bottom half of Wm into MFMA B-fragment order:
// Wtp[((ks*8+ct)*64 + l)*8 + j] = bf16(Wm[(128 + ks*32+lq*8+j)*128 + ct*16+lm]), l=lq*16+lm
__global__ void k_trans(const float* __restrict__ Wm, u16* __restrict__ Wtp) {
    int tid = blockIdx.x * 256 + threadIdx.x;   // 16384
    int j = tid & 7, l = (tid >> 3) & 63, kc = tid >> 9;
    int ks = kc >> 3, ct = kc & 7, lm = l & 15, lq = l >> 4;
    int f = ks * 32 + lq * 8 + j, c = ct * 16 + lm;
    Wtp[tid] = f2u(Wm[(128 + f) * 128 + c]);
}

// A[g] = (ce @ Wm_top) + bm, ce = (x[center]*invdeg + incident edges) @ W1 + b1
__global__ void k_A(const float* __restrict__ x, const int* __restrict__ center,
                    const float* __restrict__ invdeg, const int* __restrict__ gstart,
                    const int* __restrict__ deg, const int2* __restrict__ nme,
                    const float* __restrict__ W1, const float* __restrict__ b1,
                    const float* __restrict__ Wm, const float* __restrict__ bm,
                    float* __restrict__ A) {
    int g = blockIdx.x, t = threadIdx.x;   // 128 threads
    __shared__ float cepre[128], ce[128];
    int cg = (g << 11) + center[g];
    float v = x[cg * 128 + t] * invdeg[cg];
    int p0 = gstart[cg], p1 = p0 + deg[cg];
    for (int e = p0; e < p1; ++e) {          // usually empty (center has no in-edges)
        int2 m = nme[e];
        v += __int_as_float(m.y) * x[m.x * 128 + t];
    }
    cepre[t] = v; __syncthreads();
    float a = b1[t];
    #pragma unroll 8
    for (int f = 0; f < 128; ++f) a += cepre[f] * W1[f * 128 + t];
    ce[t] = a; __syncthreads();
    float o = bm[t];
    #pragma unroll 8
    for (int h = 0; h < 128; ++h) o += ce[h] * Wm[h * 128 + t];
    A[g * 128 + t] = o;
}

// ---------------- mask + y GEMM (MFMA), packed xy ----------------
// xy row (256 u16): group k (u16[4k..4k+4)) = { y[2k], y[2k+1], x[2k], x[2k+1] } bf16
// B-frags from global Wtp (L1-resident); sC padded stride 132 (banks = 4*lr, near-floor)
__global__ __launch_bounds__(256) void k_masky(const float* __restrict__ x,
                                               const u16* __restrict__ Wtp,
                                               const float* __restrict__ A,
                                               u16* __restrict__ xy) {
    __shared__ float sA[128];
    __shared__ float sC[4][16 * 132];
    int t = threadIdx.x;
    int tile = blockIdx.x;            // 0..2047, 64 rows each
    int g = tile >> 5;
    if (t < 128) sA[t] = A[g * 128 + t];
    __syncthreads();

    int w = t >> 6, l = t & 63;
    int lm = l & 15, lq = l >> 4;
    int row0 = tile * 64 + w * 16;
    const bf16x8* Bp = (const bf16x8*)Wtp;

    f32x4 acc[8] = {};
    #pragma unroll
    for (int ks = 0; ks < 4; ++ks) {
        const float* xp = x + (row0 + lm) * 128 + ks * 32 + lq * 8;
        float4 x0 = *(const float4*)(xp);
        float4 x1 = *(const float4*)(xp + 4);
        union { u16 u[8]; bf16x8 v; } af;
        af.u[0] = f2u(x0.x); af.u[1] = f2u(x0.y); af.u[2] = f2u(x0.z); af.u[3] = f2u(x0.w);
        af.u[4] = f2u(x1.x); af.u[5] = f2u(x1.y); af.u[6] = f2u(x1.z); af.u[7] = f2u(x1.w);
        #pragma unroll
        for (int ct = 0; ct < 8; ++ct) {
            bf16x8 b = Bp[(ks * 8 + ct) * 64 + l];
            acc[ct] = __builtin_amdgcn_mfma_f32_16x16x32_bf16(af.v, b, acc[ct], 0, 0, 0);
        }
    }

    // per-wave C tile (wave-internal LDS round-trip, no block barrier needed)
    float* myC = sC[w];
    #pragma unroll
    for (int ct = 0; ct < 8; ++ct)
        #pragma unroll
        for (int r = 0; r < 4; ++r)
            myC[(lq * 4 + r) * 132 + ct * 16 + lm] = acc[ct][r];

    int lr = l >> 2;
    int cc = (l & 3) * 32;
    int grow = row0 + lr;
    const float* xr = x + grow * 128 + cc;
    u16* orow = xy + grow * 256;
    #pragma unroll
    for (int j = 0; j < 4; ++j) {
        int c0 = cc + j * 8;
        float4 ca = *(const float4*)(myC + lr * 132 + c0);
        float4 cb = *(const float4*)(myC + lr * 132 + c0 + 4);
        float4 xa = *(const float4*)(xr + j * 8);
        float4 xd = *(const float4*)(xr + j * 8 + 4);
        float m0 = fmaxf(ca.x + sA[c0 + 0], 0.f) * xa.x;
        float m1 = fmaxf(ca.y + sA[c0 + 1], 0.f) * xa.y;
        float m2 = fmaxf(ca.z + sA[c0 + 2], 0.f) * xa.z;
        float m3 = fmaxf(ca.w + sA[c0 + 3], 0.f) * xa.w;
        float m4 = fmaxf(cb.x + sA[c0 + 4], 0.f) * xd.x;
        float m5 = fmaxf(cb.y + sA[c0 + 5], 0.f) * xd.y;
        float m6 = fmaxf(cb.z + sA[c0 + 6], 0.f) * xd.z;
        float m7 = fmaxf(cb.w + sA[c0 + 7], 0.f) * xd.w;
        uint4 q1, q2;
        q1.x = (uint32)f2u(m0) | ((uint32)f2u(m1) << 16);
        q1.y = (uint32)f2u(xa.x) | ((uint32)f2u(xa.y) << 16);
        q1.z = (uint32)f2u(m2) | ((uint32)f2u(m3) << 16);
        q1.w = (uint32)f2u(xa.z) | ((uint32)f2u(xa.w) << 16);
        q2.x = (uint32)f2u(m4) | ((uint32)f2u(m5) << 16);
        q2.y = (uint32)f2u(xd.x) | ((uint32)f2u(xd.y) << 16);
        q2.z = (uint32)f2u(m6) | ((uint32)f2u(m7) << 16);
        q2.w = (uint32)f2u(xd.z) | ((uint32)f2u(xd.w) << 16);
        *(uint4*)(orow + 2 * c0) = q1;
        *(uint4*)(orow + 2 * c0 + 8) = q2;
    }
}

// ---------------- propagation: half-wave row mapping, 2 rows per load ----------------
#define ACC8(v, cf)                                                     \
    aY0 += (cf) * lo16f((v).x); aY1 += (cf) * hi16f((v).x);             \
    aX0 += (cf) * lo16f((v).y); aX1 += (cf) * hi16f((v).y);             \
    aY2 += (cf) * lo16f((v).z); aY3 += (cf) * hi16f((v).z);             \
    aX2 += (cf) * lo16f((v).w); aX3 += (cf) * hi16f((v).w);

__global__ __launch_bounds__(256) void k_propx(const u16* __restrict__ xy,
                                               const float* __restrict__ invdeg,
                                               const int* __restrict__ pos_pn,
                                               const int2* __restrict__ nme,
                                               float* __restrict__ zp) {
    int b = blockIdx.x;
    int p = b & 7, c = b >> 3;
    int t = threadIdx.x, w = t >> 6, l = t & 63;
    int half = l >> 5, cl = l & 31;
    int i = c * 4 + w;
    float aY0 = 0.f, aY1 = 0.f, aY2 = 0.f, aY3 = 0.f;
    float aX0 = 0.f, aX1 = 0.f, aX2 = 0.f, aX3 = 0.f;

    #pragma unroll
    for (int k = 0; k < 4; ++k) {
        int gid = ((p * 8 + 2 * k + half) << 11) + i;
        float cf = invdeg[gid];
        uint4 v = *(const uint4*)(xy + gid * 256 + cl * 8);
        ACC8(v, cf)
    }

    int j = pos_pn[p * 2049 + i], jend = pos_pn[p * 2049 + i + 1];
    for (; j + 7 < jend; j += 8) {
        int2 m0 = nme[j + half];
        int2 m1 = nme[j + 2 + half];
        int2 m2 = nme[j + 4 + half];
        int2 m3 = nme[j + 6 + half];
        uint4 v0 = *(const uint4*)(xy + m0.x * 256 + cl * 8);
        uint4 v1 = *(const uint4*)(xy + m1.x * 256 + cl * 8);
        uint4 v2 = *(const uint4*)(xy + m2.x * 256 + cl * 8);
        uint4 v3 = *(const uint4*)(xy + m3.x * 256 + cl * 8);
        float c0 = __int_as_float(m0.y), c1 = __int_as_float(m1.y);
        float c2 = __int_as_float(m2.y), c3 = __int_as_float(m3.y);
        ACC8(v0, c0) ACC8(v1, c1) ACC8(v2, c2) ACC8(v3, c3)
    }
    for (; j < jend; j += 2) {
        int idx = j + half;
        if (idx < jend) {
            int2 m = nme[idx];
            uint4 v = *(const uint4*)(xy + m.x * 256 + cl * 8);
            float cf = __int_as_float(m.y);
            ACC8(v, cf)
        }
    }

    aY0 += __shfl_xor(aY0, 32, 64); aY1 += __shfl_xor(aY1, 32, 64);
    aX0 += __shfl_xor(aX0, 32, 64); aX1 += __shfl_xor(aX1, 32, 64);
    aY2 += __shfl_xor(aY2, 32, 64); aY3 += __shfl_xor(aY3, 32, 64);
    aX2 += __shfl_xor(aX2, 32, 64); aX3 += __shfl_xor(aX3, 32, 64);
    if (half == 0) {
        float* zr = zp + (((p << 11) + i) << 8) + cl * 8;
        *(float4*)(zr) = make_float4(aY0, aY1, aX0, aX1);
        *(float4*)(zr + 4) = make_float4(aY2, aY3, aX2, aX3);
    }
}

// ---------------- reduce partials + fused output matvecs ----------------
__global__ __launch_bounds__(256) void k_reduce(const float* __restrict__ zp,
                                                const float* __restrict__ W2, const float* __restrict__ b2,
                                                const float* __restrict__ W3, const float* __restrict__ b3,
                                                float* __restrict__ out) {
    int i = blockIdx.x;   // node 0..2046
    int t = threadIdx.x;
    __shared__ float zm[128], zxm[128];
    float s = 0.f;
    #pragma unroll
    for (int p = 0; p < 8; ++p) s += zp[(((p << 11) + i) << 8) + t];
    s *= (1.0f / 64.0f);
    int k = t >> 2, r = t & 3;
    if (r < 2) zm[2 * k + r] = s; else zxm[2 * k + (r - 2)] = s;
    __syncthreads();
    int cc = t & 127;
    if (t < 128) {
        float acc = b2[cc];
        #pragma unroll 8
        for (int f = 0; f < 128; ++f) acc += zm[f] * W2[f * 128 + cc];
        out[i * 128 + cc] = acc;
    } else {
        float acc = b3[cc];
        #pragma unroll 8
        for (int f = 0; f < 128; ++f) acc += (zxm[f] - zm[f]) * W3[f * 128 + cc];
        out[2047 * 128 + i * 128 + cc] = acc;
    }
}

// ---------------- launch ----------------

extern "C" void kernel_launch(void* const* d_in, const int* in_sizes, int n_in,
                              void* d_out, int out_size, void* d_ws, size_t ws_size,
                              hipStream_t stream) {
    const float* x    = (const float*)d_in[0];
    const int* ei     = (const int*)d_in[1];
    const int* center = (const int*)d_in[3];
    const float* W1 = (const float*)d_in[4];
    const float* b1 = (const float*)d_in[5];
    const float* W2 = (const float*)d_in[6];
    const float* b2 = (const float*)d_in[7];
    const float* W3 = (const float*)d_in[8];
    const float* b3 = (const float*)d_in[9];
    const float* Wm = (const float*)d_in[10];
    const float* bm = (const float*)d_in[11];
    float* out = (float*)d_out;

    char* ws = (char*)d_ws;
    int*   degc   = (int*)(ws + 0);            // 512 KB
    float* dis    = (float*)(ws + 524288);     // 512 KB
    float* invdeg = (float*)(ws + 1048576);    // 512 KB
    int*   pos_pn = (int*)(ws + 1572864);      // 65568 B (reserve 66560)
    int*   gstart = (int*)(ws + 1639424);      // 512 KB
    float* A      = (float*)(ws + 2163712);    // 32 KB
    u16*   Wtp    = (u16*)(ws + 2196480);      // 32 KB
    int2*  nme    = (int2*)(ws + 2229248);     // 8 MB
    float* zp     = (float*)(ws + 10617856);   // 16.8 MB
    u16*   xy     = (u16*)(ws + 27395072);     // 67 MB  (total ~94.5 MB)

    k_hist<<<dim3(Gg), dim3(1024), 0, stream>>>(ei, degc, dis, invdeg);
    k_scan_p<<<dim3(8), dim3(1024), 0, stream>>>(degc, pos_pn);
    k_start<<<dim3(Nn / 256), dim3(256), 0, stream>>>(degc, pos_pn, gstart);
    k_scatter<<<dim3(Gg), dim3(1024), 0, stream>>>(ei, dis, gstart, nme);
    k_trans<<<dim3(64), dim3(256), 0, stream>>>(Wm, Wtp);
    k_A<<<dim3(Gg), dim3(128), 0, stream>>>(x, center, invdeg, gstart, degc, nme, W1, b1, Wm, bm, A);
    k_masky<<<dim3(2048), dim3(256), 0, stream>>>(x, Wtp, A, xy);
    k_propx<<<dim3(4096), dim3(256), 0, stream>>>(xy, invdeg, pos_pn, nme, zp);
    k_reduce<<<dim3(Nn - 1), dim3(256), 0, stream>>>(zp, W2, b2, W3, b3, out);
}